// Round 2
// baseline (8720.968 us; speedup 1.0000x reference)
//
#include <hip/hip_runtime.h>
#include <cstdint>
#include <cstddef>

#define NB   4096
#define NN   20
#define DD   256
#define TST  30        // MAX_STEPS = int(20*1.5)
#define RPB  16        // batch rows per block
#define NTHR 512
#define SCALE 0.0625f  // 1/sqrt(256)

__device__ __forceinline__ float sigf(float x) {
    return 1.0f / (1.0f + expf(-x));
}

// ---------------------------------------------------------------------------
// keys[M][256] = node_emb_flat[M][256] @ attn_w[256][256]^T + attn_b,  M = NB*NN
// ---------------------------------------------------------------------------
__global__ __launch_bounds__(256) void keys_gemm(
    const float* __restrict__ A, const float* __restrict__ W,
    const float* __restrict__ bias, float* __restrict__ C)
{
    __shared__ float As[64][33];
    __shared__ float Bs[64][33];
    const int bm = blockIdx.x * 64;
    const int bn = blockIdx.y * 64;
    const int t  = threadIdx.x;
    const int tm = t >> 4, tn = t & 15;
    const int sr = t >> 3;
    const int sk = (t & 7) << 2;
    float acc[4][4] = {};
    for (int k0 = 0; k0 < DD; k0 += 32) {
        __syncthreads();
#pragma unroll
        for (int p = 0; p < 2; ++p) {
            const int r = sr + p * 32;
            const float4 va = *(const float4*)&A[(size_t)(bm + r) * DD + k0 + sk];
            As[r][sk] = va.x; As[r][sk + 1] = va.y; As[r][sk + 2] = va.z; As[r][sk + 3] = va.w;
            const float4 vb = *(const float4*)&W[(size_t)(bn + r) * DD + k0 + sk];
            Bs[r][sk] = vb.x; Bs[r][sk + 1] = vb.y; Bs[r][sk + 2] = vb.z; Bs[r][sk + 3] = vb.w;
        }
        __syncthreads();
#pragma unroll
        for (int k = 0; k < 32; ++k) {
            float a[4], b[4];
#pragma unroll
            for (int i = 0; i < 4; ++i) a[i] = As[tm * 4 + i][k];
#pragma unroll
            for (int j = 0; j < 4; ++j) b[j] = Bs[tn * 4 + j][k];
#pragma unroll
            for (int i = 0; i < 4; ++i)
#pragma unroll
                for (int j = 0; j < 4; ++j)
                    acc[i][j] = fmaf(a[i], b[j], acc[i][j]);
        }
    }
#pragma unroll
    for (int i = 0; i < 4; ++i) {
        const int row = bm + tm * 4 + i;
#pragma unroll
        for (int j = 0; j < 4; ++j) {
            const int col = bn + tn * 4 + j;
            C[(size_t)row * DD + col] = acc[i][j] + bias[col];
        }
    }
}

// ---------------------------------------------------------------------------
// Persistent decoder: 256 blocks x 16 rows, 512 threads (8 waves), 1 block/CU.
// Gate GEMM dataflow: weights stream global->registers (no LDS staging);
// x (inp|h) read from LDS as wave-uniform broadcasts (conflict-free).
// Thread tile: 16 rows x 4 cols x 256-k-half (kh=wave>>2 picks W_ih / W_hh).
// k-halves merged through a 64KB gates LDS buffer. c-state + tour meta in regs.
// ---------------------------------------------------------------------------
__global__ __launch_bounds__(NTHR, 2) void decode(
    const float* __restrict__ ne,    // [NB][NN][DD]
    const float* __restrict__ wih,   // [1024][256]
    const float* __restrict__ whh,   // [1024][256]
    const float* __restrict__ bih,   // [1024]
    const float* __restrict__ bhh,   // [1024]
    const float* __restrict__ dwv,   // done_w [256]
    const float* __restrict__ dbp,   // done_b scalar
    const float* __restrict__ rpp,   // revisit_penalty scalar
    const float* __restrict__ keys,  // [NB][NN][DD]  (in d_ws)
    float* __restrict__ out)         // tours [NB][31] then logps [NB][31]
{
    __shared__ float xcat[RPB][512];     // [r][0:256]=inp, [256:512]=h   (32 KB)
    __shared__ float gates[RPB][1024];   // gate pre-activations          (64 KB)

    const int t    = threadIdx.x;
    const int b0   = blockIdx.x * RPB;
    const int lane = t & 63;
    const int w    = t >> 6;        // wave 0..7
    const int kh   = t >> 8;        // 0: W_ih vs inp ; 1: W_hh vs h
    const int q    = (t >> 6) & 3;  // column group 0..3
    const int mg   = t >> 7;        // LSTM row group 0..3
    const int ni3  = t & 127;       // LSTM dim within 128-group
    const int xb   = kh << 8;       // x base: 0 (inp) or 256 (h)

    const float done_b = dbp[0];
    const float rp     = rpp[0];

    // per-thread LSTM bias sums: g -> col (g>>1)*256 + ((g&1)<<7) + ni3
    float bsv[8];
#pragma unroll
    for (int g = 0; g < 8; ++g) {
        const int j = (g >> 1) * 256 + ((g & 1) << 7) + ni3;
        bsv[g] = bih[j] + bhh[j];
    }
    const float4 dv = *(const float4*)&dwv[lane * 4];

    // weight row base pointers (4 gate columns per thread)
    const float* Wb = kh ? whh : wih;
    const float* p0 = Wb + (size_t)(q * 256 + 0 * 64 + lane) * DD;
    const float* p1 = Wb + (size_t)(q * 256 + 1 * 64 + lane) * DD;
    const float* p2 = Wb + (size_t)(q * 256 + 2 * 64 + lane) * DD;
    const float* p3 = Wb + (size_t)(q * 256 + 3 * 64 + lane) * DD;

    // ---- init: h=0, inp = mean over nodes ----
    for (int idx = t; idx < RPB * 256; idx += NTHR)
        xcat[idx >> 8][256 + (idx & 255)] = 0.0f;
#pragma unroll
    for (int rr = 0; rr < 2; ++rr) {
        const int r = w * 2 + rr;
        const int b = b0 + r;
        float sx = 0.f, sy = 0.f, sz = 0.f, sw = 0.f;
        for (int n = 0; n < NN; ++n) {
            const float4 v = *(const float4*)&ne[((size_t)b * NN + n) * DD + lane * 4];
            sx += v.x; sy += v.y; sz += v.z; sw += v.w;
        }
        float4 m4;
        m4.x = sx / 20.0f; m4.y = sy / 20.0f; m4.z = sz / 20.0f; m4.w = sw / 20.0f;
        *(float4*)&xcat[r][lane * 4] = m4;
    }

    float creg[4][2] = {};           // c-state: rows mg*4+i, dims {ni3, ni3+128}
    unsigned vm[2] = {0u, 0u};       // per-wave tour meta (rows w*2, w*2+1)
    int un[2] = {0, 0}, fn[2] = {0, 0}, cm[2] = {0, 0};

    auto ldw = [&](int k, float4 (&W)[4][2]) {
#pragma unroll
        for (int j = 0; j < 2; ++j) {
            W[0][j] = *(const float4*)(p0 + k + j * 4);
            W[1][j] = *(const float4*)(p1 + k + j * 4);
            W[2][j] = *(const float4*)(p2 + k + j * 4);
            W[3][j] = *(const float4*)(p3 + k + j * 4);
        }
    };

    for (int step = 0; step < TST; ++step) {
        __syncthreads();   // xcat (inp+h) ready; gates free

        // ---- gate GEMM: acc[r][c] = sum_k x[r][xb+k] * W[col][k], k-half ----
        float acc[16][4] = {};
        float4 wA[4][2], wB[4][2];
        ldw(0, wA);
#pragma unroll 1
        for (int kc = 0; kc < 32; kc += 2) {
            const int kA = kc * 8;
            ldw(kA + 8, wB);
            // FMA chunk A
#pragma unroll
            for (int g = 0; g < 2; ++g)
#pragma unroll
                for (int r = 0; r < 16; ++r) {
                    const float4 x4 = *(const float4*)&xcat[r][xb + kA + g * 4];
#pragma unroll
                    for (int c = 0; c < 4; ++c) {
                        acc[r][c] = fmaf(x4.x, wA[c][g].x, acc[r][c]);
                        acc[r][c] = fmaf(x4.y, wA[c][g].y, acc[r][c]);
                        acc[r][c] = fmaf(x4.z, wA[c][g].z, acc[r][c]);
                        acc[r][c] = fmaf(x4.w, wA[c][g].w, acc[r][c]);
                    }
                }
            if (kc + 2 < 32) ldw(kA + 16, wA);
            // FMA chunk B
#pragma unroll
            for (int g = 0; g < 2; ++g)
#pragma unroll
                for (int r = 0; r < 16; ++r) {
                    const float4 x4 = *(const float4*)&xcat[r][xb + kA + 8 + g * 4];
#pragma unroll
                    for (int c = 0; c < 4; ++c) {
                        acc[r][c] = fmaf(x4.x, wB[c][g].x, acc[r][c]);
                        acc[r][c] = fmaf(x4.y, wB[c][g].y, acc[r][c]);
                        acc[r][c] = fmaf(x4.z, wB[c][g].z, acc[r][c]);
                        acc[r][c] = fmaf(x4.w, wB[c][g].w, acc[r][c]);
                    }
                }
        }

        // ---- merge k-halves through LDS ----
        if (kh == 0) {
#pragma unroll
            for (int r = 0; r < 16; ++r)
#pragma unroll
                for (int c = 0; c < 4; ++c)
                    gates[r][q * 256 + c * 64 + lane] = acc[r][c];
        }
        __syncthreads();
        if (kh == 1) {
#pragma unroll
            for (int r = 0; r < 16; ++r)
#pragma unroll
                for (int c = 0; c < 4; ++c)
                    gates[r][q * 256 + c * 64 + lane] += acc[r][c];
        }
        __syncthreads();

        // ---- LSTM elementwise (rows mg*4..+3, dims {ni3, ni3+128}) ----
#pragma unroll
        for (int i = 0; i < 4; ++i) {
            const int r = (mg << 2) + i;
#pragma unroll
            for (int dd = 0; dd < 2; ++dd) {
                const int d = ni3 + (dd << 7);
                const float gi = gates[r][d]       + bsv[0 + dd];
                const float gf = gates[r][d + 256] + bsv[2 + dd];
                const float gg = gates[r][d + 512] + bsv[4 + dd];
                const float go = gates[r][d + 768] + bsv[6 + dd];
                const float co = creg[i][dd];
                const float cn = sigf(gf) * co + sigf(gi) * tanhf(gg);
                const float hn = sigf(go) * tanhf(cn);
                creg[i][dd] = cn;
                xcat[r][256 + d] = hn;
            }
        }
        __syncthreads();   // h2 ready

        // ---- per-row scoring: wave w owns rows w*2, w*2+1 ----
#pragma unroll
        for (int rr = 0; rr < 2; ++rr) {
            const int r = w * 2 + rr;
            const int b = b0 + r;
            const float4 h4 = *(const float4*)&xcat[r][256 + lane * 4];

            float pd = h4.x * dv.x + h4.y * dv.y + h4.z * dv.z + h4.w * dv.w;
#pragma unroll
            for (int o = 32; o >= 1; o >>= 1) pd += __shfl_xor(pd, o);

            float ps[NN];
            const float* kb = keys + (size_t)b * NN * DD + lane * 4;
#pragma unroll
            for (int n = 0; n < NN; ++n) {
                const float4 kv = *(const float4*)(kb + n * DD);
                ps[n] = h4.x * kv.x + h4.y * kv.y + h4.z * kv.z + h4.w * kv.w;
            }
#pragma unroll
            for (int n = 0; n < NN; ++n) {
                float v = ps[n];
#pragma unroll
                for (int o = 32; o >= 1; o >>= 1) v += __shfl_xor(v, o);
                ps[n] = v;  // all lanes now hold full dot for node n
            }

            const float dprob = 1.0f / (1.0f + expf(-(pd + done_b)));
            const int elig = (!cm[rr]) && (un[rr] >= NN) && (step >= NN);
            const int cm2  = cm[rr] || (elig && (dprob > 0.5f));

            float sv[NN];
#pragma unroll
            for (int n = 0; n < NN; ++n) {
                float s = ps[n] * SCALE;
                if ((!cm2) && (un[rr] < NN) && ((vm[rr] >> n) & 1u)) s = rp;
                if (cm2) s = (n == fn[rr]) ? 100.0f : -1e9f;
                sv[n] = s;
            }
            float m = sv[0];
#pragma unroll
            for (int n = 1; n < NN; ++n) m = fmaxf(m, sv[n]);
            float e[NN]; float se = 0.0f;
#pragma unroll
            for (int n = 0; n < NN; ++n) { e[n] = expf(sv[n] - m); se += e[n]; }
            // probs + first-index argmax (IEEE division per element, as reference)
            float pmax = e[0] / se; int idx = 0;
#pragma unroll
            for (int n = 1; n < NN; ++n) {
                const float pn = e[n] / se;
                if (pn > pmax) { pmax = pn; idx = n; }
            }
            const int curr  = cm2 ? fn[rr] : idx;
            const float pc  = cm2 ? 1.0f : pmax;
            const float lp  = logf(pc + 1e-10f);

            if (step == 0) fn[rr] = curr;
            const int newly = (!cm2) && !((vm[rr] >> curr) & 1u);
            if (!cm2) vm[rr] |= (1u << curr);
            un[rr] += newly;
            cm[rr] = cm2;

            if (lane == 0) {
                out[(size_t)b * (TST + 1) + step] = (float)curr;
                out[(size_t)NB * (TST + 1) + (size_t)b * (TST + 1) + step] = lp;
            }
            // gather next input
            const float4 nv = *(const float4*)&ne[((size_t)b * NN + curr) * DD + lane * 4];
            *(float4*)&xcat[r][lane * 4] = nv;
        }
    }

    // ---- tail: column TST ----
#pragma unroll
    for (int rr = 0; rr < 2; ++rr) {
        const int b = b0 + w * 2 + rr;
        if (lane == 0) {
            out[(size_t)b * (TST + 1) + TST] = cm[rr] ? 0.0f : (float)fn[rr];
            out[(size_t)NB * (TST + 1) + (size_t)b * (TST + 1) + TST] = 0.0f;
        }
    }
}

// ---------------------------------------------------------------------------
extern "C" void kernel_launch(void* const* d_in, const int* in_sizes, int n_in,
                              void* d_out, int out_size, void* d_ws, size_t ws_size,
                              hipStream_t stream) {
    (void)in_sizes; (void)n_in; (void)out_size;
    const float* ne  = (const float*)d_in[0];
    // d_in[1] = mask (unused by forward)
    const float* wih = (const float*)d_in[2];
    const float* whh = (const float*)d_in[3];
    const float* bih = (const float*)d_in[4];
    const float* bhh = (const float*)d_in[5];
    const float* aw  = (const float*)d_in[6];
    const float* ab  = (const float*)d_in[7];
    const float* dw  = (const float*)d_in[8];
    const float* db  = (const float*)d_in[9];
    const float* rp  = (const float*)d_in[10];
    // d_in[11] = greedy (always greedy path)
    float* out  = (float*)d_out;
    float* keys = (float*)d_ws;           // [NB*NN*DD] floats = 80 MB
    if (ws_size < (size_t)NB * NN * DD * sizeof(float)) return;

    keys_gemm<<<dim3((NB * NN) / 64, DD / 64), 256, 0, stream>>>(ne, aw, ab, keys);
    decode<<<dim3(NB / RPB), NTHR, 0, stream>>>(ne, wih, whh, bih, bhh, dw, db, rp, keys, out);
}

// Round 3
// 4664.955 us; speedup vs baseline: 1.8695x; 1.8695x over previous
//
#include <hip/hip_runtime.h>
#include <cstdint>
#include <cstddef>

#define NB   4096
#define NN   20
#define DD   256
#define TST  30        // MAX_STEPS = int(20*1.5)
#define RPB  16        // batch rows per block
#define NTHR 512
#define SCALE 0.0625f  // 1/sqrt(256)

__device__ __forceinline__ float sigf(float x) {
    return 1.0f / (1.0f + expf(-x));
}

// ---------------------------------------------------------------------------
// keys[M][256] = node_emb_flat[M][256] @ attn_w[256][256]^T + attn_b,  M = NB*NN
// ---------------------------------------------------------------------------
__global__ __launch_bounds__(256) void keys_gemm(
    const float* __restrict__ A, const float* __restrict__ W,
    const float* __restrict__ bias, float* __restrict__ C)
{
    __shared__ float As[64][33];
    __shared__ float Bs[64][33];
    const int bm = blockIdx.x * 64;
    const int bn = blockIdx.y * 64;
    const int t  = threadIdx.x;
    const int tm = t >> 4, tn = t & 15;
    const int sr = t >> 3;
    const int sk = (t & 7) << 2;
    float acc[4][4] = {};
    for (int k0 = 0; k0 < DD; k0 += 32) {
        __syncthreads();
#pragma unroll
        for (int p = 0; p < 2; ++p) {
            const int r = sr + p * 32;
            const float4 va = *(const float4*)&A[(size_t)(bm + r) * DD + k0 + sk];
            As[r][sk] = va.x; As[r][sk + 1] = va.y; As[r][sk + 2] = va.z; As[r][sk + 3] = va.w;
            const float4 vb = *(const float4*)&W[(size_t)(bn + r) * DD + k0 + sk];
            Bs[r][sk] = vb.x; Bs[r][sk + 1] = vb.y; Bs[r][sk + 2] = vb.z; Bs[r][sk + 3] = vb.w;
        }
        __syncthreads();
#pragma unroll
        for (int k = 0; k < 32; ++k) {
            float a[4], b[4];
#pragma unroll
            for (int i = 0; i < 4; ++i) a[i] = As[tm * 4 + i][k];
#pragma unroll
            for (int j = 0; j < 4; ++j) b[j] = Bs[tn * 4 + j][k];
#pragma unroll
            for (int i = 0; i < 4; ++i)
#pragma unroll
                for (int j = 0; j < 4; ++j)
                    acc[i][j] = fmaf(a[i], b[j], acc[i][j]);
        }
    }
#pragma unroll
    for (int i = 0; i < 4; ++i) {
        const int row = bm + tm * 4 + i;
#pragma unroll
        for (int j = 0; j < 4; ++j) {
            const int col = bn + tn * 4 + j;
            C[(size_t)row * DD + col] = acc[i][j] + bias[col];
        }
    }
}

// ---------------------------------------------------------------------------
// Persistent decoder: 256 blocks x 16 rows, 512 threads (8 waves), 1 block/CU.
// Weights stream global->registers (L1/L2-resident); x (inp|h) read from LDS
// as wave-uniform broadcasts (conflict-free). Thread tile: 8 rows x 8 cols x
// 256-k-half. Mapping: rg=t>>8 (row group), kh=(t>>7)&1 (W_ih/W_hh half),
// cg=t&127; cols = cg + 128*j (lane-stride-1 gate merge, conflict-free).
// ---------------------------------------------------------------------------
__global__ __launch_bounds__(NTHR, 1) void decode(
    const float* __restrict__ ne,    // [NB][NN][DD]
    const float* __restrict__ wih,   // [1024][256]
    const float* __restrict__ whh,   // [1024][256]
    const float* __restrict__ bih,   // [1024]
    const float* __restrict__ bhh,   // [1024]
    const float* __restrict__ dwv,   // done_w [256]
    const float* __restrict__ dbp,   // done_b scalar
    const float* __restrict__ rpp,   // revisit_penalty scalar
    const float* __restrict__ keys,  // [NB][NN][DD]  (in d_ws)
    float* __restrict__ out)         // tours [NB][31] then logps [NB][31]
{
    __shared__ float xcat[RPB][512];     // [r][0:256]=inp, [256:512]=h   (32 KB)
    __shared__ float gates[RPB][1024];   // gate pre-activations          (64 KB)

    const int t    = threadIdx.x;
    const int b0   = blockIdx.x * RPB;
    const int lane = t & 63;
    const int w    = t >> 6;        // wave 0..7
    const int rg   = t >> 8;        // row group: rows rg*8 .. rg*8+7
    const int kh   = (t >> 7) & 1;  // 0: W_ih vs inp ; 1: W_hh vs h
    const int cg   = t & 127;       // cols cg + 128*j, j=0..7
    const int mg   = t >> 7;        // LSTM row group 0..3
    const int ni3  = t & 127;       // LSTM dim within 128-group
    const int xb   = kh << 8;       // x base: 0 (inp) or 256 (h)
    const int rbase = rg << 3;

    const float done_b = dbp[0];
    const float rp     = rpp[0];

    // per-thread LSTM bias sums: g -> col (g>>1)*256 + ((g&1)<<7) + ni3
    float bsv[8];
#pragma unroll
    for (int g = 0; g < 8; ++g) {
        const int j = (g >> 1) * 256 + ((g & 1) << 7) + ni3;
        bsv[g] = bih[j] + bhh[j];
    }
    const float4 dv = *(const float4*)&dwv[lane * 4];

    // weight row pointers: 8 gate columns per thread, stride-128 rows
    const float* Wb = kh ? whh : wih;
    const float* wp[8];
#pragma unroll
    for (int j = 0; j < 8; ++j) wp[j] = Wb + (size_t)(cg + (j << 7)) * DD;

    // ---- init: h=0, inp = mean over nodes ----
    for (int idx = t; idx < RPB * 256; idx += NTHR)
        xcat[idx >> 8][256 + (idx & 255)] = 0.0f;
#pragma unroll
    for (int rr = 0; rr < 2; ++rr) {
        const int r = w * 2 + rr;
        const int b = b0 + r;
        float sx = 0.f, sy = 0.f, sz = 0.f, sw = 0.f;
        for (int n = 0; n < NN; ++n) {
            const float4 v = *(const float4*)&ne[((size_t)b * NN + n) * DD + lane * 4];
            sx += v.x; sy += v.y; sz += v.z; sw += v.w;
        }
        float4 m4;
        m4.x = sx / 20.0f; m4.y = sy / 20.0f; m4.z = sz / 20.0f; m4.w = sw / 20.0f;
        *(float4*)&xcat[r][lane * 4] = m4;
    }

    float creg[4][2] = {};           // c-state: rows mg*4+i, dims {ni3, ni3+128}
    unsigned vm[2] = {0u, 0u};       // per-wave tour meta (rows w*2, w*2+1)
    int un[2] = {0, 0}, fn[2] = {0, 0}, cm[2] = {0, 0};

    for (int step = 0; step < TST; ++step) {
        __syncthreads();   // xcat (inp+h) ready; gates free

        // ---- gate GEMM: acc[r][j] = sum_k x[rbase+r][xb+k] * W[cg+128j][k]
        float acc[8][8] = {};
#pragma unroll 2
        for (int kc = 0; kc < 64; ++kc) {
            float4 wv[8];
#pragma unroll
            for (int j = 0; j < 8; ++j)
                wv[j] = *(const float4*)(wp[j] + (kc << 2));
#pragma unroll
            for (int r = 0; r < 8; ++r) {
                const float4 x4 = *(const float4*)&xcat[rbase + r][xb + (kc << 2)];
#pragma unroll
                for (int j = 0; j < 8; ++j) {
                    acc[r][j] = fmaf(x4.x, wv[j].x, acc[r][j]);
                    acc[r][j] = fmaf(x4.y, wv[j].y, acc[r][j]);
                    acc[r][j] = fmaf(x4.z, wv[j].z, acc[r][j]);
                    acc[r][j] = fmaf(x4.w, wv[j].w, acc[r][j]);
                }
            }
        }

        // ---- merge k-halves through LDS (lane-stride-1, conflict-free) ----
        if (kh == 0) {
#pragma unroll
            for (int r = 0; r < 8; ++r)
#pragma unroll
                for (int j = 0; j < 8; ++j)
                    gates[rbase + r][cg + (j << 7)] = acc[r][j];
        }
        __syncthreads();
        if (kh == 1) {
#pragma unroll
            for (int r = 0; r < 8; ++r)
#pragma unroll
                for (int j = 0; j < 8; ++j)
                    gates[rbase + r][cg + (j << 7)] += acc[r][j];
        }
        __syncthreads();

        // ---- LSTM elementwise (rows mg*4..+3, dims {ni3, ni3+128}) ----
#pragma unroll
        for (int i = 0; i < 4; ++i) {
            const int r = (mg << 2) + i;
#pragma unroll
            for (int dd = 0; dd < 2; ++dd) {
                const int d = ni3 + (dd << 7);
                const float gi = gates[r][d]       + bsv[0 + dd];
                const float gf = gates[r][d + 256] + bsv[2 + dd];
                const float gg = gates[r][d + 512] + bsv[4 + dd];
                const float go = gates[r][d + 768] + bsv[6 + dd];
                const float co = creg[i][dd];
                const float cn = sigf(gf) * co + sigf(gi) * tanhf(gg);
                const float hn = sigf(go) * tanhf(cn);
                creg[i][dd] = cn;
                xcat[r][256 + d] = hn;
            }
        }
        __syncthreads();   // h2 ready

        // ---- per-row scoring: wave w owns rows w*2, w*2+1 ----
#pragma unroll
        for (int rr = 0; rr < 2; ++rr) {
            const int r = w * 2 + rr;
            const int b = b0 + r;
            const float4 h4 = *(const float4*)&xcat[r][256 + lane * 4];

            float pd = h4.x * dv.x + h4.y * dv.y + h4.z * dv.z + h4.w * dv.w;
#pragma unroll
            for (int o = 32; o >= 1; o >>= 1) pd += __shfl_xor(pd, o);

            float ps[NN];
            const float* kb = keys + (size_t)b * NN * DD + lane * 4;
#pragma unroll
            for (int n = 0; n < NN; ++n) {
                const float4 kv = *(const float4*)(kb + n * DD);
                ps[n] = h4.x * kv.x + h4.y * kv.y + h4.z * kv.z + h4.w * kv.w;
            }
#pragma unroll
            for (int n = 0; n < NN; ++n) {
                float v = ps[n];
#pragma unroll
                for (int o = 32; o >= 1; o >>= 1) v += __shfl_xor(v, o);
                ps[n] = v;  // all lanes now hold full dot for node n
            }

            const float dprob = 1.0f / (1.0f + expf(-(pd + done_b)));
            const int elig = (!cm[rr]) && (un[rr] >= NN) && (step >= NN);
            const int cm2  = cm[rr] || (elig && (dprob > 0.5f));

            float sv[NN];
#pragma unroll
            for (int n = 0; n < NN; ++n) {
                float s = ps[n] * SCALE;
                if ((!cm2) && (un[rr] < NN) && ((vm[rr] >> n) & 1u)) s = rp;
                if (cm2) s = (n == fn[rr]) ? 100.0f : -1e9f;
                sv[n] = s;
            }
            float m = sv[0];
#pragma unroll
            for (int n = 1; n < NN; ++n) m = fmaxf(m, sv[n]);
            float e[NN]; float se = 0.0f;
#pragma unroll
            for (int n = 0; n < NN; ++n) { e[n] = expf(sv[n] - m); se += e[n]; }
            // probs + first-index argmax (IEEE division per element, as reference)
            float pmax = e[0] / se; int idx = 0;
#pragma unroll
            for (int n = 1; n < NN; ++n) {
                const float pn = e[n] / se;
                if (pn > pmax) { pmax = pn; idx = n; }
            }
            const int curr  = cm2 ? fn[rr] : idx;
            const float pc  = cm2 ? 1.0f : pmax;
            const float lp  = logf(pc + 1e-10f);

            if (step == 0) fn[rr] = curr;
            const int newly = (!cm2) && !((vm[rr] >> curr) & 1u);
            if (!cm2) vm[rr] |= (1u << curr);
            un[rr] += newly;
            cm[rr] = cm2;

            if (lane == 0) {
                out[(size_t)b * (TST + 1) + step] = (float)curr;
                out[(size_t)NB * (TST + 1) + (size_t)b * (TST + 1) + step] = lp;
            }
            // gather next input
            const float4 nv = *(const float4*)&ne[((size_t)b * NN + curr) * DD + lane * 4];
            *(float4*)&xcat[r][lane * 4] = nv;
        }
    }

    // ---- tail: column TST ----
#pragma unroll
    for (int rr = 0; rr < 2; ++rr) {
        const int b = b0 + w * 2 + rr;
        if (lane == 0) {
            out[(size_t)b * (TST + 1) + TST] = cm[rr] ? 0.0f : (float)fn[rr];
            out[(size_t)NB * (TST + 1) + (size_t)b * (TST + 1) + TST] = 0.0f;
        }
    }
}

// ---------------------------------------------------------------------------
extern "C" void kernel_launch(void* const* d_in, const int* in_sizes, int n_in,
                              void* d_out, int out_size, void* d_ws, size_t ws_size,
                              hipStream_t stream) {
    (void)in_sizes; (void)n_in; (void)out_size;
    const float* ne  = (const float*)d_in[0];
    // d_in[1] = mask (unused by forward)
    const float* wih = (const float*)d_in[2];
    const float* whh = (const float*)d_in[3];
    const float* bih = (const float*)d_in[4];
    const float* bhh = (const float*)d_in[5];
    const float* aw  = (const float*)d_in[6];
    const float* ab  = (const float*)d_in[7];
    const float* dw  = (const float*)d_in[8];
    const float* db  = (const float*)d_in[9];
    const float* rp  = (const float*)d_in[10];
    // d_in[11] = greedy (always greedy path)
    float* out  = (float*)d_out;
    float* keys = (float*)d_ws;           // [NB*NN*DD] floats = 80 MB
    if (ws_size < (size_t)NB * NN * DD * sizeof(float)) return;

    keys_gemm<<<dim3((NB * NN) / 64, DD / 64), 256, 0, stream>>>(ne, aw, ab, keys);
    decode<<<dim3(NB / RPB), NTHR, 0, stream>>>(ne, wih, whh, bih, bhh, dw, db, rp, keys, out);
}